// Round 1
// 990.169 us; speedup vs baseline: 1.1517x; 1.1517x over previous
//
#include <hip/hip_runtime.h>
#include <hip/hip_bf16.h>

typedef __bf16 bf16_t;
typedef __bf16 bf16x8 __attribute__((ext_vector_type(8)));
typedef __bf16 bf16x4 __attribute__((ext_vector_type(4)));
typedef float floatx4 __attribute__((ext_vector_type(4)));

#define M_DIM 16384   // B*S = 4*4096
#define N_DIM 4096    // D_out
#define K_DIM 4096    // D_in
#define R_DIM 16      // LoRA rank
#define LORA_SCALE 2.0f   // alpha/r = 32/16

// global -> LDS direct DMA, 16B per lane. LDS dest = wave-uniform base + lane*16.
__device__ __forceinline__ void async_copy16(void* lds, const void* gptr) {
  __builtin_amdgcn_global_load_lds(
      (__attribute__((address_space(1))) void*)(gptr),
      (__attribute__((address_space(3))) void*)(lds),
      16, 0, 0);
}

// Barrier with hard compiler memory fence on both sides: no LDS/VMEM op may be
// moved across it (gload_lds issue order and ds_read phase placement are part
// of the race-freedom ledger of the 8-phase schedule below).
__device__ __forceinline__ void block_barrier() {
  asm volatile("" ::: "memory");
  __builtin_amdgcn_s_barrier();
  asm volatile("" ::: "memory");
}

// ---------------------------------------------------------------------------
// fp32 -> bf16 elementwise convert, 8 elements per thread.
// ---------------------------------------------------------------------------
__global__ void cvt_kernel(const float* __restrict__ src,
                           bf16_t* __restrict__ dst, int n8) {
  const int idx = blockIdx.x * blockDim.x + threadIdx.x;
  if (idx >= n8) return;
  const float4 a = ((const float4*)src)[idx * 2 + 0];
  const float4 b = ((const float4*)src)[idx * 2 + 1];
  bf16x8 v;
  v[0] = (bf16_t)a.x; v[1] = (bf16_t)a.y; v[2] = (bf16_t)a.z; v[3] = (bf16_t)a.w;
  v[4] = (bf16_t)b.x; v[5] = (bf16_t)b.y; v[6] = (bf16_t)b.z; v[7] = (bf16_t)b.w;
  ((bf16x8*)dst)[idx] = v;
}

// ---------------------------------------------------------------------------
// T[m][r] = SCALE * sum_k X[m][k] * lora_A[k][r]  — bf16 X (fast path)
// ---------------------------------------------------------------------------
__launch_bounds__(256, 2)
__global__ void lora_xa_bf16(const bf16_t* __restrict__ X,
                             const float* __restrict__ A,
                             bf16_t* __restrict__ T) {
  __shared__ bf16_t Xs[64 * 64];   // 8 KB
  __shared__ bf16_t At[16 * 64];   // 2 KB, [r][k] transposed
  const int tid  = threadIdx.x;
  const int wave = tid >> 6;
  const int lane = tid & 63;
  const int quad = lane >> 4;
  const int l15  = lane & 15;
  const int gm0  = blockIdx.x * 64;

  floatx4 acc = {0.f, 0.f, 0.f, 0.f};
  for (int k0 = 0; k0 < K_DIM; k0 += 64) {
#pragma unroll
    for (int j = 0; j < 2; ++j) {
      const int i   = wave * 2 + j;
      const int row = i * 8 + (lane >> 3);
      const int col = (lane & 7) * 8;
      async_copy16(&Xs[i * 512], X + (size_t)(gm0 + row) * K_DIM + k0 + col);
    }
    {
      const int c  = tid >> 4;
      const int k4 = (tid & 15) * 4;
#pragma unroll
      for (int j = 0; j < 4; ++j)
        At[c * 64 + k4 + j] = (bf16_t)A[(size_t)(k0 + k4 + j) * R_DIM + c];
    }
    __syncthreads();
#pragma unroll
    for (int h = 0; h < 2; ++h) {
      const int kk = h * 32;
      const bf16x8 a = *(const bf16x8*)&Xs[(wave * 16 + l15) * 64 + kk + quad * 8];
      const bf16x8 b = *(const bf16x8*)&At[l15 * 64 + kk + quad * 8];
      acc = __builtin_amdgcn_mfma_f32_16x16x32_bf16(a, b, acc, 0, 0, 0);
    }
    __syncthreads();
  }
#pragma unroll
  for (int r = 0; r < 4; ++r) {
    const int row = gm0 + wave * 16 + quad * 4 + r;
    T[(size_t)row * R_DIM + l15] = (bf16_t)(LORA_SCALE * acc[r]);
  }
}

// ---------------------------------------------------------------------------
// T prepass reading fp32 X directly (fallback path).
// ---------------------------------------------------------------------------
__launch_bounds__(256, 2)
__global__ void lora_xa_f32(const float* __restrict__ X,
                            const float* __restrict__ A,
                            bf16_t* __restrict__ T) {
  __shared__ bf16_t Xs[64 * 64];
  __shared__ bf16_t At[16 * 64];
  const int tid  = threadIdx.x;
  const int wave = tid >> 6;
  const int lane = tid & 63;
  const int quad = lane >> 4;
  const int l15  = lane & 15;
  const int gm0  = blockIdx.x * 64;

  floatx4 acc = {0.f, 0.f, 0.f, 0.f};
  for (int k0 = 0; k0 < K_DIM; k0 += 64) {
#pragma unroll
    for (int i = 0; i < 4; ++i) {
      const int idx  = tid + i * 256;     // [0,1024)
      const int row  = idx >> 4;          // 16 float4 per row (64 k-elems)
      const int colf = idx & 15;
      const float4 v = *(const float4*)&X[(size_t)(gm0 + row) * K_DIM + k0 + colf * 4];
      bf16x4 w;
      w[0] = (bf16_t)v.x; w[1] = (bf16_t)v.y; w[2] = (bf16_t)v.z; w[3] = (bf16_t)v.w;
      *(bf16x4*)&Xs[row * 64 + colf * 4] = w;
    }
    {
      const int c  = tid >> 4;
      const int k4 = (tid & 15) * 4;
#pragma unroll
      for (int j = 0; j < 4; ++j)
        At[c * 64 + k4 + j] = (bf16_t)A[(size_t)(k0 + k4 + j) * R_DIM + c];
    }
    __syncthreads();
#pragma unroll
    for (int h = 0; h < 2; ++h) {
      const int kk = h * 32;
      const bf16x8 a = *(const bf16x8*)&Xs[(wave * 16 + l15) * 64 + kk + quad * 8];
      const bf16x8 b = *(const bf16x8*)&At[l15 * 64 + kk + quad * 8];
      acc = __builtin_amdgcn_mfma_f32_16x16x32_bf16(a, b, acc, 0, 0, 0);
    }
    __syncthreads();
  }
#pragma unroll
  for (int r = 0; r < 4; ++r) {
    const int row = gm0 + wave * 16 + quad * 4 + r;
    T[(size_t)row * R_DIM + l15] = (bf16_t)(LORA_SCALE * acc[r]);
  }
}

// ---------------------------------------------------------------------------
// Main kernel, fast path: 256x256 tile, BK=64, 8 waves (2x4), 8-phase
// schedule with counted vmcnt (T3+T4), st-swizzled LDS (T2), setprio (T5),
// XCD-aware block swizzle (T1). LDS: 2 x (A 32KB + B 32KB) = 128 KiB dynamic.
//
// Region ledger (per iteration i, tiles t=2i -> buf0, t+1=2i+1 -> buf1):
//   quadrant order per tile: (aq,bq) = (0,0),(0,1),(1,1),(1,0)
//   -> A-q0 (rows 0-63) and A-q2 (rows 128-191) of the buffer being read are
//      dead after phase 2; everything else dead after phase 4.
//   ph1: stage t+1's remaining 6 units -> buf1 (all of buf1 dead since prev iter)
//   ph3: stage t+2's A-q0,A-q2 -> buf0 (dead after ph2)
//   ph4: fence vmcnt(2) (the 2 = ph3's pair) -> t+1 fully landed; barrier
//   ph5: stage t+2's remaining 6 -> buf0 (all dead after ph4)
//   ph7: stage t+3's A-q0,A-q2 -> buf1 (dead after ph6)
//   ph8: fence vmcnt(2) (the 2 = ph7's pair) -> t+2 fully landed; barrier
// Swizzle: LDS 16B-slot s_phys = s_log ^ (row & 7), applied on the global
// SOURCE address at stage time (gload_lds dest is linear) and on ds_read.
// ---------------------------------------------------------------------------
#define LD_A(AQ)                                                               \
  _Pragma("unroll") for (int i_ = 0; i_ < 4; ++i_) {                           \
    const int r_ = (rowA + ((AQ) * 4 + i_) * 16) * 64;                         \
    af[i_][0] = *(const bf16x8*)&Ab[r_ + ((quad    ) ^ swz) * 8];              \
    af[i_][1] = *(const bf16x8*)&Ab[r_ + ((quad + 4) ^ swz) * 8];              \
  }

#define LD_B(BQ)                                                               \
  _Pragma("unroll") for (int j_ = 0; j_ < 2; ++j_) {                           \
    const int r_ = (rowB + ((BQ) * 2 + j_) * 16) * 64;                         \
    bfr[j_][0] = *(const bf16x8*)&Bb[r_ + ((quad    ) ^ swz) * 8];             \
    bfr[j_][1] = *(const bf16x8*)&Bb[r_ + ((quad + 4) ^ swz) * 8];             \
  }

#define MFMA16(AQ, BQ)                                                         \
  __builtin_amdgcn_s_setprio(1);                                               \
  _Pragma("unroll") for (int i_ = 0; i_ < 4; ++i_)                             \
  _Pragma("unroll") for (int j_ = 0; j_ < 2; ++j_) {                           \
    acc[(AQ) * 4 + i_][(BQ) * 2 + j_] =                                        \
        __builtin_amdgcn_mfma_f32_16x16x32_bf16(                               \
            af[i_][0], bfr[j_][0], acc[(AQ) * 4 + i_][(BQ) * 2 + j_], 0, 0, 0);\
    acc[(AQ) * 4 + i_][(BQ) * 2 + j_] =                                        \
        __builtin_amdgcn_mfma_f32_16x16x32_bf16(                               \
            af[i_][1], bfr[j_][1], acc[(AQ) * 4 + i_][(BQ) * 2 + j_], 0, 0, 0);\
  }                                                                            \
  __builtin_amdgcn_s_setprio(0);

__launch_bounds__(512, 2)
__global__ void main8_bf16(const bf16_t* __restrict__ X,
                           const bf16_t* __restrict__ W,
                           const float* __restrict__ bias,
                           const float* __restrict__ loraB,
                           const bf16_t* __restrict__ T,
                           float* __restrict__ out) {
  extern __shared__ bf16_t lds[];
  bf16_t* As = lds;           // [2][256*64]
  bf16_t* Bs = lds + 32768;   // [2][256*64]

  const int tid  = threadIdx.x;
  const int wave = tid >> 6;
  const int lane = tid & 63;
  const int quad = lane >> 4;
  const int l15  = lane & 15;
  const int swz  = l15 & 7;
  const int wr   = wave >> 2;   // 0..1  -> 128 output rows
  const int wc   = wave & 3;    // 0..3  -> 64 output cols

  // T1: XCD-aware swizzle; 1024 blocks, 8 XCDs, 1024 % 8 == 0 (bijective).
  const int b   = blockIdx.x;
  const int swb = (b & 7) * 128 + (b >> 3);
  const int gm  = (swb >> 4) * 256;   // 64 m-blocks
  const int gn  = (swb & 15) * 256;   // 16 n-blocks

  const int rowA = wr * 128 + l15;
  const int rowB = wc * 64 + l15;

  // Staging geometry: one unit = 64 rows x 64 k (8KB) = 1 gload_lds of 16B/lane.
  // Thread covers (row srow, phys slot lane&7); source column pre-swizzled.
  const int srow  = wave * 8 + (lane >> 3);           // row within a 64-row unit
  const int sslot = (lane & 7) ^ ((lane >> 3) & 7);   // inverse-swizzled src slot
  const bf16_t* gA = X + (size_t)(gm + srow) * K_DIM + sslot * 8;
  const bf16_t* gB = W + (size_t)(gn + srow) * K_DIM + sslot * 8;

  auto stageA = [&](int bsel, int u, int t) {
    async_copy16(As + bsel * 16384 + u * 4096 + wave * 512,
                 gA + (size_t)u * 64 * K_DIM + t * 64);
  };
  auto stageB = [&](int bsel, int u, int t) {
    async_copy16(Bs + bsel * 16384 + u * 4096 + wave * 512,
                 gB + (size_t)u * 64 * K_DIM + t * 64);
  };

  floatx4 acc[8][4];
#pragma unroll
  for (int i = 0; i < 8; ++i)
#pragma unroll
    for (int j = 0; j < 4; ++j) acc[i][j] = (floatx4){0.f, 0.f, 0.f, 0.f};

  // Prologue: tile0 fully (buf0) + tile1's early A pair (buf1). 10 issued,
  // wait all but the newest 2 (= tile0 landed).
#pragma unroll
  for (int u = 0; u < 4; ++u) stageA(0, u, 0);
#pragma unroll
  for (int u = 0; u < 4; ++u) stageB(0, u, 0);
  stageA(1, 0, 1); stageA(1, 2, 1);
  asm volatile("s_waitcnt vmcnt(2)" ::: "memory");
  block_barrier();

  const int NITER = K_DIM / 128;   // 32
  for (int i = 0; i < NITER; ++i) {
    const int t1 = 2 * i + 1, t2 = 2 * i + 2, t3 = 2 * i + 3;
    const bool last = (i == NITER - 1);
    bf16x8 af[4][2];    // current aq's A fragments (held across 2 phases)
    bf16x8 bfr[2][2];   // current bq's B fragments

    // ---------------- first half: tile 2i from buf0 ----------------
    {
      const bf16_t* Ab = As;
      const bf16_t* Bb = Bs;
      // ph1 (0,0): stage t+1's remaining 6 units into buf1
      LD_A(0); LD_B(0);
      stageA(1, 1, t1); stageA(1, 3, t1);
      stageB(1, 0, t1); stageB(1, 1, t1); stageB(1, 2, t1); stageB(1, 3, t1);
      block_barrier(); MFMA16(0, 0); block_barrier();
      // ph2 (0,1): reuse af
      LD_B(1);
      block_barrier(); MFMA16(0, 1); block_barrier();
      // ph3 (1,1): reuse bfr; stage t+2's early A pair into buf0 (dead regions)
      LD_A(1);
      if (!last) { stageA(0, 0, t2); stageA(0, 2, t2); }
      block_barrier(); MFMA16(1, 1); block_barrier();
      // ph4 (1,0): fence -> tile t+1 fully landed
      LD_B(0);
      block_barrier(); MFMA16(1, 0);
      if (last) asm volatile("s_waitcnt vmcnt(0)" ::: "memory");
      else      asm volatile("s_waitcnt vmcnt(2)" ::: "memory");
      block_barrier();
    }
    // ---------------- second half: tile 2i+1 from buf1 ----------------
    {
      const bf16_t* Ab = As + 16384;
      const bf16_t* Bb = Bs + 16384;
      // ph5 (0,0): stage t+2's remaining 6 units into buf0 (all dead)
      LD_A(0); LD_B(0);
      if (!last) {
        stageA(0, 1, t2); stageA(0, 3, t2);
        stageB(0, 0, t2); stageB(0, 1, t2); stageB(0, 2, t2); stageB(0, 3, t2);
      }
      block_barrier(); MFMA16(0, 0); block_barrier();
      // ph6 (0,1)
      LD_B(1);
      block_barrier(); MFMA16(0, 1); block_barrier();
      // ph7 (1,1): stage t+3's early A pair into buf1 (dead after ph6)
      LD_A(1);
      if (!last) { stageA(1, 0, t3); stageA(1, 2, t3); }
      block_barrier(); MFMA16(1, 1); block_barrier();
      // ph8 (1,0): fence -> tile t+2 fully landed
      LD_B(0);
      block_barrier(); MFMA16(1, 0);
      if (last) asm volatile("s_waitcnt vmcnt(0)" ::: "memory");
      else      asm volatile("s_waitcnt vmcnt(2)" ::: "memory");
      block_barrier();
    }
  }

  // ---------------- LoRA tail: one K=32 MFMA step (T | 0) x (loraB^T | 0) ---
  if (tid < 256) {
    const int row = tid;
    const bf16_t* tp = T + (size_t)(gm + row) * R_DIM;
    *(uint4*)&As[row * 32]      = *(const uint4*)tp;
    *(uint4*)&As[row * 32 + 8]  = *(const uint4*)(tp + 8);
    *(uint4*)&As[row * 32 + 16] = make_uint4(0, 0, 0, 0);
    *(uint4*)&As[row * 32 + 24] = make_uint4(0, 0, 0, 0);
  } else {
    const int n = tid - 256;
#pragma unroll
    for (int r = 0; r < R_DIM; ++r)
      Bs[n * 32 + r] = (bf16_t)loraB[(size_t)r * N_DIM + gn + n];
    *(uint4*)&Bs[n * 32 + 16] = make_uint4(0, 0, 0, 0);
    *(uint4*)&Bs[n * 32 + 24] = make_uint4(0, 0, 0, 0);
  }
  __syncthreads();
  {
    bf16x8 afr[8]; bf16x8 bft[4];
#pragma unroll
    for (int im = 0; im < 8; ++im)
      afr[im] = *(const bf16x8*)&As[(wr * 128 + im * 16 + l15) * 32 + quad * 8];
#pragma unroll
    for (int in = 0; in < 4; ++in)
      bft[in] = *(const bf16x8*)&Bs[(wc * 64 + in * 16 + l15) * 32 + quad * 8];
#pragma unroll
    for (int im = 0; im < 8; ++im)
#pragma unroll
      for (int in = 0; in < 4; ++in)
        acc[im][in] = __builtin_amdgcn_mfma_f32_16x16x32_bf16(
            afr[im], bft[in], acc[im][in], 0, 0, 0);
  }

  // ---------------- epilogue: bias add + store ----------------
#pragma unroll
  for (int in = 0; in < 4; ++in) {
    const int col = gn + wc * 64 + in * 16 + l15;
    const float bv = bias[col];
#pragma unroll
    for (int im = 0; im < 8; ++im) {
      const int row0 = gm + wr * 128 + im * 16 + quad * 4;
#pragma unroll
      for (int r = 0; r < 4; ++r)
        out[(size_t)(row0 + r) * N_DIM + col] = acc[im][in][r] + bv;
    }
  }
}

// Main kernel, fallback: fp32 X/W loaded to regs, converted, ds_write staged.
__launch_bounds__(256, 2)
__global__ void main_f32(const float* __restrict__ X,
                         const float* __restrict__ W,
                         const float* __restrict__ bias,
                         const float* __restrict__ loraB,
                         const bf16_t* __restrict__ T,
                         float* __restrict__ out) {
  __shared__ bf16_t As[128 * 32];
  __shared__ bf16_t Bs[128 * 32];
  const int tid  = threadIdx.x;
  const int wave = tid >> 6;
  const int lane = tid & 63;
  const int quad = lane >> 4;
  const int l15  = lane & 15;
  const int gm   = (blockIdx.x >> 5) * 128;
  const int gn   = (blockIdx.x & 31) * 128;
  const int wr   = wave >> 1;
  const int wc   = wave & 1;

  floatx4 acc[4][4];
#pragma unroll
  for (int i = 0; i < 4; ++i)
#pragma unroll
    for (int j = 0; j < 4; ++j) acc[i][j] = (floatx4){0.f, 0.f, 0.f, 0.f};

  for (int k0 = 0; k0 < K_DIM; k0 += 32) {
#pragma unroll
    for (int i = 0; i < 4; ++i) {
      const int idx  = tid + i * 256;    // [0,1024)
      const int row  = idx >> 3;         // 8 float4 per row (32 k-elems)
      const int colf = idx & 7;
      const float4 va = *(const float4*)&X[(size_t)(gm + row) * K_DIM + k0 + colf * 4];
      const float4 vb = *(const float4*)&W[(size_t)(gn + row) * K_DIM + k0 + colf * 4];
      bf16x4 wa, wb;
      wa[0] = (bf16_t)va.x; wa[1] = (bf16_t)va.y; wa[2] = (bf16_t)va.z; wa[3] = (bf16_t)va.w;
      wb[0] = (bf16_t)vb.x; wb[1] = (bf16_t)vb.y; wb[2] = (bf16_t)vb.z; wb[3] = (bf16_t)vb.w;
      *(bf16x4*)&As[row * 32 + colf * 4] = wa;
      *(bf16x4*)&Bs[row * 32 + colf * 4] = wb;
    }
    __syncthreads();
    bf16x8 a_frag[4], b_frag[4];
#pragma unroll
    for (int im = 0; im < 4; ++im)
      a_frag[im] = *(const bf16x8*)&As[(wr * 64 + im * 16 + l15) * 32 + quad * 8];
#pragma unroll
    for (int in = 0; in < 4; ++in)
      b_frag[in] = *(const bf16x8*)&Bs[(wc * 64 + in * 16 + l15) * 32 + quad * 8];
#pragma unroll
    for (int im = 0; im < 4; ++im)
#pragma unroll
      for (int in = 0; in < 4; ++in)
        acc[im][in] = __builtin_amdgcn_mfma_f32_16x16x32_bf16(
            a_frag[im], b_frag[in], acc[im][in], 0, 0, 0);
    __syncthreads();
  }

  if (tid < 128) {
    const int row = tid;
    const bf16_t* tp = T + (size_t)(gm + row) * R_DIM;
    *(uint4*)&As[row * 32]      = *(const uint4*)tp;
    *(uint4*)&As[row * 32 + 8]  = *(const uint4*)(tp + 8);
    *(uint4*)&As[row * 32 + 16] = make_uint4(0, 0, 0, 0);
    *(uint4*)&As[row * 32 + 24] = make_uint4(0, 0, 0, 0);
  } else {
    const int n = tid - 128;
#pragma unroll
    for (int r = 0; r < R_DIM; ++r)
      Bs[n * 32 + r] = (bf16_t)loraB[(size_t)r * N_DIM + gn + n];
    *(uint4*)&Bs[n * 32 + 16] = make_uint4(0, 0, 0, 0);
    *(uint4*)&Bs[n * 32 + 24] = make_uint4(0, 0, 0, 0);
  }
  __syncthreads();
  {
    bf16x8 a_frag[4], b_frag[4];
#pragma unroll
    for (int im = 0; im < 4; ++im)
      a_frag[im] = *(const bf16x8*)&As[(wr * 64 + im * 16 + l15) * 32 + quad * 8];
#pragma unroll
    for (int in = 0; in < 4; ++in)
      b_frag[in] = *(const bf16x8*)&Bs[(wc * 64 + in * 16 + l15) * 32 + quad * 8];
#pragma unroll
    for (int im = 0; im < 4; ++im)
#pragma unroll
      for (int in = 0; in < 4; ++in)
        acc[im][in] = __builtin_amdgcn_mfma_f32_16x16x32_bf16(
            a_frag[im], b_frag[in], acc[im][in], 0, 0, 0);
  }

#pragma unroll
  for (int in = 0; in < 4; ++in) {
    const int col = gn + wc * 64 + in * 16 + l15;
    const float bv = bias[col];
#pragma unroll
    for (int im = 0; im < 4; ++im) {
      const int row0 = gm + wr * 64 + im * 16 + quad * 4;
#pragma unroll
      for (int r = 0; r < 4; ++r)
        out[(size_t)(row0 + r) * N_DIM + col] = acc[im][in][r] + bv;
    }
  }
}

extern "C" void kernel_launch(void* const* d_in, const int* in_sizes, int n_in,
                              void* d_out, int out_size, void* d_ws, size_t ws_size,
                              hipStream_t stream) {
  const float* X    = (const float*)d_in[0];  // [16384][4096]
  const float* W    = (const float*)d_in[1];  // [4096][4096], out = X @ W^T
  const float* bias = (const float*)d_in[2];  // [4096]
  const float* lA   = (const float*)d_in[3];  // [4096][16]
  const float* lB   = (const float*)d_in[4];  // [16][4096]
  float* out = (float*)d_out;

  bf16_t* T = (bf16_t*)d_ws;                                  // 512 KB
  const size_t offX = 512 * 1024;
  const size_t offW = offX + (size_t)M_DIM * K_DIM * sizeof(bf16_t);
  const size_t need = offW + (size_t)N_DIM * K_DIM * sizeof(bf16_t);

  if (ws_size >= need) {
    bf16_t* Xb = (bf16_t*)((char*)d_ws + offX);
    bf16_t* Wb = (bf16_t*)((char*)d_ws + offW);
    {
      const int n8 = M_DIM * K_DIM / 8;
      cvt_kernel<<<(n8 + 255) / 256, 256, 0, stream>>>(X, Xb, n8);
    }
    {
      const int n8 = N_DIM * K_DIM / 8;
      cvt_kernel<<<(n8 + 255) / 256, 256, 0, stream>>>(W, Wb, n8);
    }
    lora_xa_bf16<<<M_DIM / 64, 256, 0, stream>>>(Xb, lA, T);
    static bool attr_set = false;
    if (!attr_set) {
      (void)hipFuncSetAttribute(reinterpret_cast<const void*>(main8_bf16),
                                hipFuncAttributeMaxDynamicSharedMemorySize,
                                131072);
      attr_set = true;
    }
    main8_bf16<<<(M_DIM / 256) * (N_DIM / 256), 512, 131072, stream>>>(
        Xb, Wb, bias, lB, T, out);
  } else {
    lora_xa_f32<<<M_DIM / 64, 256, 0, stream>>>(X, lA, T);
    main_f32<<<(M_DIM / 128) * (N_DIM / 128), 256, 0, stream>>>(
        X, W, bias, lB, T, out);
  }
}

// Round 2
// 967.264 us; speedup vs baseline: 1.1790x; 1.0237x over previous
//
#include <hip/hip_runtime.h>
#include <hip/hip_bf16.h>

typedef __bf16 bf16_t;
typedef __bf16 bf16x8 __attribute__((ext_vector_type(8)));
typedef __bf16 bf16x4 __attribute__((ext_vector_type(4)));
typedef float floatx4 __attribute__((ext_vector_type(4)));

#define M_DIM 16384   // B*S = 4*4096
#define N_DIM 4096    // D_out
#define K_DIM 4096    // D_in
#define R_DIM 16      // LoRA rank
#define LORA_SCALE 2.0f   // alpha/r = 32/16

// global -> LDS direct DMA, 16B per lane. LDS dest = wave-uniform base + lane*16.
__device__ __forceinline__ void async_copy16(void* lds, const void* gptr) {
  __builtin_amdgcn_global_load_lds(
      (__attribute__((address_space(1))) void*)(gptr),
      (__attribute__((address_space(3))) void*)(lds),
      16, 0, 0);
}

__device__ __forceinline__ void block_barrier() {
  asm volatile("" ::: "memory");
  __builtin_amdgcn_s_barrier();
  asm volatile("" ::: "memory");
}

// ---------------------------------------------------------------------------
// fp32 -> bf16 elementwise convert, 8 elements per thread (used for W).
// ---------------------------------------------------------------------------
__global__ void cvt_kernel(const float* __restrict__ src,
                           bf16_t* __restrict__ dst, int n8) {
  const int idx = blockIdx.x * blockDim.x + threadIdx.x;
  if (idx >= n8) return;
  const float4 a = ((const float4*)src)[idx * 2 + 0];
  const float4 b = ((const float4*)src)[idx * 2 + 1];
  bf16x8 v;
  v[0] = (bf16_t)a.x; v[1] = (bf16_t)a.y; v[2] = (bf16_t)a.z; v[3] = (bf16_t)a.w;
  v[4] = (bf16_t)b.x; v[5] = (bf16_t)b.y; v[6] = (bf16_t)b.z; v[7] = (bf16_t)b.w;
  ((bf16x8*)dst)[idx] = v;
}

// ---------------------------------------------------------------------------
// Fused prepass: reads fp32 X once; writes bf16 Xb AND
// T[m][r] = SCALE * sum_k X[m][k] * lora_A[k][r].
// Eliminates the separate cvt pass over X (saves a 256+128 MB round trip).
// ---------------------------------------------------------------------------
__launch_bounds__(256, 2)
__global__ void lora_xa_cvt(const float* __restrict__ X,
                            const float* __restrict__ A,
                            bf16_t* __restrict__ T,
                            bf16_t* __restrict__ Xb) {
  __shared__ bf16_t Xs[64 * 64];   // 8 KB
  __shared__ bf16_t At[16 * 64];   // 2 KB, [r][k] transposed
  const int tid  = threadIdx.x;
  const int wave = tid >> 6;
  const int lane = tid & 63;
  const int quad = lane >> 4;
  const int l15  = lane & 15;
  const int gm0  = blockIdx.x * 64;

  floatx4 acc = {0.f, 0.f, 0.f, 0.f};
  for (int k0 = 0; k0 < K_DIM; k0 += 64) {
#pragma unroll
    for (int i = 0; i < 4; ++i) {
      const int idx  = tid + i * 256;     // [0,1024)
      const int row  = idx >> 4;          // 16 float4 per row (64 k-elems)
      const int colf = idx & 15;
      const float4 v = *(const float4*)&X[(size_t)(gm0 + row) * K_DIM + k0 + colf * 4];
      bf16x4 w;
      w[0] = (bf16_t)v.x; w[1] = (bf16_t)v.y; w[2] = (bf16_t)v.z; w[3] = (bf16_t)v.w;
      *(bf16x4*)&Xs[row * 64 + colf * 4] = w;
      *(bf16x4*)&Xb[(size_t)(gm0 + row) * K_DIM + k0 + colf * 4] = w;
    }
    {
      const int c  = tid >> 4;
      const int k4 = (tid & 15) * 4;
#pragma unroll
      for (int j = 0; j < 4; ++j)
        At[c * 64 + k4 + j] = (bf16_t)A[(size_t)(k0 + k4 + j) * R_DIM + c];
    }
    __syncthreads();
#pragma unroll
    for (int h = 0; h < 2; ++h) {
      const int kk = h * 32;
      const bf16x8 a = *(const bf16x8*)&Xs[(wave * 16 + l15) * 64 + kk + quad * 8];
      const bf16x8 b = *(const bf16x8*)&At[l15 * 64 + kk + quad * 8];
      acc = __builtin_amdgcn_mfma_f32_16x16x32_bf16(a, b, acc, 0, 0, 0);
    }
    __syncthreads();
  }
#pragma unroll
  for (int r = 0; r < 4; ++r) {
    const int row = gm0 + wave * 16 + quad * 4 + r;
    T[(size_t)row * R_DIM + l15] = (bf16_t)(LORA_SCALE * acc[r]);
  }
}

// ---------------------------------------------------------------------------
// T prepass reading fp32 X directly (fallback path, no Xb workspace).
// ---------------------------------------------------------------------------
__launch_bounds__(256, 2)
__global__ void lora_xa_f32(const float* __restrict__ X,
                            const float* __restrict__ A,
                            bf16_t* __restrict__ T) {
  __shared__ bf16_t Xs[64 * 64];
  __shared__ bf16_t At[16 * 64];
  const int tid  = threadIdx.x;
  const int wave = tid >> 6;
  const int lane = tid & 63;
  const int quad = lane >> 4;
  const int l15  = lane & 15;
  const int gm0  = blockIdx.x * 64;

  floatx4 acc = {0.f, 0.f, 0.f, 0.f};
  for (int k0 = 0; k0 < K_DIM; k0 += 64) {
#pragma unroll
    for (int i = 0; i < 4; ++i) {
      const int idx  = tid + i * 256;
      const int row  = idx >> 4;
      const int colf = idx & 15;
      const float4 v = *(const float4*)&X[(size_t)(gm0 + row) * K_DIM + k0 + colf * 4];
      bf16x4 w;
      w[0] = (bf16_t)v.x; w[1] = (bf16_t)v.y; w[2] = (bf16_t)v.z; w[3] = (bf16_t)v.w;
      *(bf16x4*)&Xs[row * 64 + colf * 4] = w;
    }
    {
      const int c  = tid >> 4;
      const int k4 = (tid & 15) * 4;
#pragma unroll
      for (int j = 0; j < 4; ++j)
        At[c * 64 + k4 + j] = (bf16_t)A[(size_t)(k0 + k4 + j) * R_DIM + c];
    }
    __syncthreads();
#pragma unroll
    for (int h = 0; h < 2; ++h) {
      const int kk = h * 32;
      const bf16x8 a = *(const bf16x8*)&Xs[(wave * 16 + l15) * 64 + kk + quad * 8];
      const bf16x8 b = *(const bf16x8*)&At[l15 * 64 + kk + quad * 8];
      acc = __builtin_amdgcn_mfma_f32_16x16x32_bf16(a, b, acc, 0, 0, 0);
    }
    __syncthreads();
  }
#pragma unroll
  for (int r = 0; r < 4; ++r) {
    const int row = gm0 + wave * 16 + quad * 4 + r;
    T[(size_t)row * R_DIM + l15] = (bf16_t)(LORA_SCALE * acc[r]);
  }
}

// ---------------------------------------------------------------------------
// Main kernel: 256x256 tile, BK=64, 8 waves (2x4), 8-phase counted-vmcnt
// schedule (T3+T4), XOR-swizzled LDS (T2), setprio (T5), XCD swizzle (T1).
// LDS: 2 x (A 32KB + B 32KB) = 128 KiB dynamic.
//
// Region ledger (iteration i: tile 2i in buf0, 2i+1 in buf1; quadrant order
// (aq,bq) = (0,0),(0,1),(1,1),(1,0); A-units 0,2 of a buffer are dead after
// its (0,*) phases, units 1,3 after its (1,1) phase; B-units after the last
// (*,0)/(*,1) LDS read of that buffer):
//   ph1: LD_A0,LD_B0 buf0   | stage t1 A1,A3 -> buf1 (dead since prev ph7)
//   ph2: LD_B1      buf0    | stage t1 B0,B1 -> buf1 (dead since prev ph8)
//   ph3: LD_A1      buf0    | stage t1 B2,B3 -> buf1
//   ph4: LD_B0      buf0    | stage t2 A0,A2 -> buf0 (dead after ph1)
//        fence vmcnt(2): only ph4's pair outstanding => t1 fully landed
//   ph5-ph8: mirror on buf1, staging t2 remainder -> buf0, t3 A0,A2 -> buf1,
//        fence vmcnt(2) => t2 fully landed.
// Swizzle: 16B-slot s_phys = s_log ^ (row & 7); applied on the global SOURCE
// address at stage time (gload_lds dest must stay linear) and on ds_read.
// ---------------------------------------------------------------------------
#define LD_A(AQ)                                                               \
  _Pragma("unroll") for (int i_ = 0; i_ < 4; ++i_) {                           \
    const int r_ = (rowA + ((AQ) * 4 + i_) * 16) * 64;                         \
    af[i_][0] = *(const bf16x8*)&Ab[r_ + ((quad    ) ^ swz) * 8];              \
    af[i_][1] = *(const bf16x8*)&Ab[r_ + ((quad + 4) ^ swz) * 8];              \
  }

#define LD_B(BQ)                                                               \
  _Pragma("unroll") for (int j_ = 0; j_ < 2; ++j_) {                           \
    const int r_ = (rowB + ((BQ) * 2 + j_) * 16) * 64;                         \
    bfr[j_][0] = *(const bf16x8*)&Bb[r_ + ((quad    ) ^ swz) * 8];             \
    bfr[j_][1] = *(const bf16x8*)&Bb[r_ + ((quad + 4) ^ swz) * 8];             \
  }

// k-half OUTER: dependent MFMAs on the same acc are 8 apart (8 independent
// accumulation chains in between) instead of back-to-back.
#define MFMA16(AQ, BQ)                                                         \
  __builtin_amdgcn_s_setprio(1);                                               \
  _Pragma("unroll") for (int h_ = 0; h_ < 2; ++h_)                             \
  _Pragma("unroll") for (int i_ = 0; i_ < 4; ++i_)                             \
  _Pragma("unroll") for (int j_ = 0; j_ < 2; ++j_)                             \
    acc[(AQ) * 4 + i_][(BQ) * 2 + j_] =                                        \
        __builtin_amdgcn_mfma_f32_16x16x32_bf16(                               \
            af[i_][h_], bfr[j_][h_], acc[(AQ) * 4 + i_][(BQ) * 2 + j_],        \
            0, 0, 0);                                                          \
  __builtin_amdgcn_s_setprio(0);

__launch_bounds__(512, 2)
__global__ void main8_bf16(const bf16_t* __restrict__ X,
                           const bf16_t* __restrict__ W,
                           const float* __restrict__ bias,
                           const float* __restrict__ loraB,
                           const bf16_t* __restrict__ T,
                           float* __restrict__ out) {
  extern __shared__ bf16_t lds[];
  bf16_t* As = lds;           // [2][256*64]
  bf16_t* Bs = lds + 32768;   // [2][256*64]

  const int tid  = threadIdx.x;
  const int wave = tid >> 6;
  const int lane = tid & 63;
  const int quad = lane >> 4;
  const int l15  = lane & 15;
  const int swz  = l15 & 7;
  const int wr   = wave >> 2;   // 0..1  -> 128 output rows
  const int wc   = wave & 3;    // 0..3  -> 64 output cols

  // T1: XCD-aware swizzle; 1024 blocks, 8 XCDs, 1024 % 8 == 0 (bijective).
  const int b   = blockIdx.x;
  const int swb = (b & 7) * 128 + (b >> 3);
  const int gm  = (swb >> 4) * 256;   // 64 m-blocks
  const int gn  = (swb & 15) * 256;   // 16 n-blocks

  const int rowA = wr * 128 + l15;
  const int rowB = wc * 64 + l15;

  // Staging geometry: one unit = 64 rows x 64 k (8KB); each of 8 waves
  // contributes one gload_lds of 16B/lane. Source slot pre-inverse-swizzled.
  const int srow  = wave * 8 + (lane >> 3);
  const int sslot = (lane & 7) ^ ((lane >> 3) & 7);
  const bf16_t* gA = X + (size_t)(gm + srow) * K_DIM + sslot * 8;
  const bf16_t* gB = W + (size_t)(gn + srow) * K_DIM + sslot * 8;

  auto stageA = [&](int bsel, int u, int t) {
    async_copy16(As + bsel * 16384 + u * 4096 + wave * 512,
                 gA + (size_t)u * 64 * K_DIM + t * 64);
  };
  auto stageB = [&](int bsel, int u, int t) {
    async_copy16(Bs + bsel * 16384 + u * 4096 + wave * 512,
                 gB + (size_t)u * 64 * K_DIM + t * 64);
  };

  floatx4 acc[8][4];
#pragma unroll
  for (int i = 0; i < 8; ++i)
#pragma unroll
    for (int j = 0; j < 4; ++j) acc[i][j] = (floatx4){0.f, 0.f, 0.f, 0.f};

  // Prologue: tile0 fully (buf0) + tile1's A0,A2 pair (buf1).
#pragma unroll
  for (int u = 0; u < 4; ++u) stageA(0, u, 0);
#pragma unroll
  for (int u = 0; u < 4; ++u) stageB(0, u, 0);
  stageA(1, 0, 1); stageA(1, 2, 1);
  asm volatile("s_waitcnt vmcnt(2)" ::: "memory");
  block_barrier();

  const int NITER = K_DIM / 128;   // 32
  for (int i = 0; i < NITER; ++i) {
    const int t1 = 2 * i + 1, t2 = 2 * i + 2, t3 = 2 * i + 3;
    const bool last = (i == NITER - 1);
    bf16x8 af[4][2];
    bf16x8 bfr[2][2];

    // ---------------- first half: tile 2i from buf0 ----------------
    {
      const bf16_t* Ab = As;
      const bf16_t* Bb = Bs;
      // ph1 (0,0)
      LD_A(0); LD_B(0);
      stageA(1, 1, t1); stageA(1, 3, t1);
      asm volatile("s_waitcnt lgkmcnt(8)" ::: "memory");
      block_barrier(); MFMA16(0, 0); block_barrier();
      // ph2 (0,1)
      LD_B(1);
      stageB(1, 0, t1); stageB(1, 1, t1);
      block_barrier(); MFMA16(0, 1); block_barrier();
      // ph3 (1,1)
      LD_A(1);
      stageB(1, 2, t1); stageB(1, 3, t1);
      block_barrier(); MFMA16(1, 1); block_barrier();
      // ph4 (1,0): fence -> t1 fully landed in buf1
      LD_B(0);
      if (!last) { stageA(0, 0, t2); stageA(0, 2, t2); }
      block_barrier(); MFMA16(1, 0);
      if (last) asm volatile("s_waitcnt vmcnt(0)" ::: "memory");
      else      asm volatile("s_waitcnt vmcnt(2)" ::: "memory");
      block_barrier();
    }
    // ---------------- second half: tile 2i+1 from buf1 ----------------
    {
      const bf16_t* Ab = As + 16384;
      const bf16_t* Bb = Bs + 16384;
      // ph5 (0,0)
      LD_A(0); LD_B(0);
      if (!last) { stageA(0, 1, t2); stageA(0, 3, t2); }
      asm volatile("s_waitcnt lgkmcnt(8)" ::: "memory");
      block_barrier(); MFMA16(0, 0); block_barrier();
      // ph6 (0,1)
      LD_B(1);
      if (!last) { stageB(0, 0, t2); stageB(0, 1, t2); }
      block_barrier(); MFMA16(0, 1); block_barrier();
      // ph7 (1,1)
      LD_A(1);
      if (!last) { stageB(0, 2, t2); stageB(0, 3, t2); }
      block_barrier(); MFMA16(1, 1); block_barrier();
      // ph8 (1,0): fence -> t2 fully landed in buf0
      LD_B(0);
      if (!last) { stageA(1, 0, t3); stageA(1, 2, t3); }
      block_barrier(); MFMA16(1, 0);
      if (last) asm volatile("s_waitcnt vmcnt(0)" ::: "memory");
      else      asm volatile("s_waitcnt vmcnt(2)" ::: "memory");
      block_barrier();
    }
  }

  // ---------------- LoRA tail: one K=32 MFMA step (T | 0) x (loraB^T | 0) ---
  if (tid < 256) {
    const int row = tid;
    const bf16_t* tp = T + (size_t)(gm + row) * R_DIM;
    *(uint4*)&As[row * 32]      = *(const uint4*)tp;
    *(uint4*)&As[row * 32 + 8]  = *(const uint4*)(tp + 8);
    *(uint4*)&As[row * 32 + 16] = make_uint4(0, 0, 0, 0);
    *(uint4*)&As[row * 32 + 24] = make_uint4(0, 0, 0, 0);
  } else {
    const int n = tid - 256;
#pragma unroll
    for (int r = 0; r < R_DIM; ++r)
      Bs[n * 32 + r] = (bf16_t)loraB[(size_t)r * N_DIM + gn + n];
    *(uint4*)&Bs[n * 32 + 16] = make_uint4(0, 0, 0, 0);
    *(uint4*)&Bs[n * 32 + 24] = make_uint4(0, 0, 0, 0);
  }
  __syncthreads();
  {
    bf16x8 afr[8]; bf16x8 bft[4];
#pragma unroll
    for (int im = 0; im < 8; ++im)
      afr[im] = *(const bf16x8*)&As[(wr * 128 + im * 16 + l15) * 32 + quad * 8];
#pragma unroll
    for (int in = 0; in < 4; ++in)
      bft[in] = *(const bf16x8*)&Bs[(wc * 64 + in * 16 + l15) * 32 + quad * 8];
#pragma unroll
    for (int im = 0; im < 8; ++im)
#pragma unroll
      for (int in = 0; in < 4; ++in)
        acc[im][in] = __builtin_amdgcn_mfma_f32_16x16x32_bf16(
            afr[im], bft[in], acc[im][in], 0, 0, 0);
  }

  // ---------------- epilogue: bias add + store ----------------
#pragma unroll
  for (int in = 0; in < 4; ++in) {
    const int col = gn + wc * 64 + in * 16 + l15;
    const float bv = bias[col];
#pragma unroll
    for (int im = 0; im < 8; ++im) {
      const int row0 = gm + wr * 128 + im * 16 + quad * 4;
#pragma unroll
      for (int r = 0; r < 4; ++r)
        out[(size_t)(row0 + r) * N_DIM + col] = acc[im][in][r] + bv;
    }
  }
}

// Main kernel, fallback: fp32 X/W loaded to regs, converted, ds_write staged.
__launch_bounds__(256, 2)
__global__ void main_f32(const float* __restrict__ X,
                         const float* __restrict__ W,
                         const float* __restrict__ bias,
                         const float* __restrict__ loraB,
                         const bf16_t* __restrict__ T,
                         float* __restrict__ out) {
  __shared__ bf16_t As[128 * 32];
  __shared__ bf16_t Bs[128 * 32];
  const int tid  = threadIdx.x;
  const int wave = tid >> 6;
  const int lane = tid & 63;
  const int quad = lane >> 4;
  const int l15  = lane & 15;
  const int gm   = (blockIdx.x >> 5) * 128;
  const int gn   = (blockIdx.x & 31) * 128;
  const int wr   = wave >> 1;
  const int wc   = wave & 1;

  floatx4 acc[4][4];
#pragma unroll
  for (int i = 0; i < 4; ++i)
#pragma unroll
    for (int j = 0; j < 4; ++j) acc[i][j] = (floatx4){0.f, 0.f, 0.f, 0.f};

  for (int k0 = 0; k0 < K_DIM; k0 += 32) {
#pragma unroll
    for (int i = 0; i < 4; ++i) {
      const int idx  = tid + i * 256;
      const int row  = idx >> 3;
      const int colf = idx & 7;
      const float4 va = *(const float4*)&X[(size_t)(gm + row) * K_DIM + k0 + colf * 4];
      const float4 vb = *(const float4*)&W[(size_t)(gn + row) * K_DIM + k0 + colf * 4];
      bf16x4 wa, wb;
      wa[0] = (bf16_t)va.x; wa[1] = (bf16_t)va.y; wa[2] = (bf16_t)va.z; wa[3] = (bf16_t)va.w;
      wb[0] = (bf16_t)vb.x; wb[1] = (bf16_t)vb.y; wb[2] = (bf16_t)vb.z; wb[3] = (bf16_t)vb.w;
      *(bf16x4*)&As[row * 32 + colf * 4] = wa;
      *(bf16x4*)&Bs[row * 32 + colf * 4] = wb;
    }
    __syncthreads();
    bf16x8 a_frag[4], b_frag[4];
#pragma unroll
    for (int im = 0; im < 4; ++im)
      a_frag[im] = *(const bf16x8*)&As[(wr * 64 + im * 16 + l15) * 32 + quad * 8];
#pragma unroll
    for (int in = 0; in < 4; ++in)
      b_frag[in] = *(const bf16x8*)&Bs[(wc * 64 + in * 16 + l15) * 32 + quad * 8];
#pragma unroll
    for (int im = 0; im < 4; ++im)
#pragma unroll
      for (int in = 0; in < 4; ++in)
        acc[im][in] = __builtin_amdgcn_mfma_f32_16x16x32_bf16(
            a_frag[im], b_frag[in], acc[im][in], 0, 0, 0);
    __syncthreads();
  }

  if (tid < 128) {
    const int row = tid;
    const bf16_t* tp = T + (size_t)(gm + row) * R_DIM;
    *(uint4*)&As[row * 32]      = *(const uint4*)tp;
    *(uint4*)&As[row * 32 + 8]  = *(const uint4*)(tp + 8);
    *(uint4*)&As[row * 32 + 16] = make_uint4(0, 0, 0, 0);
    *(uint4*)&As[row * 32 + 24] = make_uint4(0, 0, 0, 0);
  } else {
    const int n = tid - 128;
#pragma unroll
    for (int r = 0; r < R_DIM; ++r)
      Bs[n * 32 + r] = (bf16_t)loraB[(size_t)r * N_DIM + gn + n];
    *(uint4*)&Bs[n * 32 + 16] = make_uint4(0, 0, 0, 0);
    *(uint4*)&Bs[n * 32 + 24] = make_uint4(0, 0, 0, 0);
  }
  __syncthreads();
  {
    bf16x8 a_frag[4], b_frag[4];
#pragma unroll
    for (int im = 0; im < 4; ++im)
      a_frag[im] = *(const bf16x8*)&As[(wr * 64 + im * 16 + l15) * 32 + quad * 8];
#pragma unroll
    for (int in = 0; in < 4; ++in)
      b_frag[in] = *(const bf16x8*)&Bs[(wc * 64 + in * 16 + l15) * 32 + quad * 8];
#pragma unroll
    for (int im = 0; im < 4; ++im)
#pragma unroll
      for (int in = 0; in < 4; ++in)
        acc[im][in] = __builtin_amdgcn_mfma_f32_16x16x32_bf16(
            a_frag[im], b_frag[in], acc[im][in], 0, 0, 0);
  }

#pragma unroll
  for (int in = 0; in < 4; ++in) {
    const int col = gn + wc * 64 + in * 16 + l15;
    const float bv = bias[col];
#pragma unroll
    for (int im = 0; im < 4; ++im) {
      const int row0 = gm + wr * 64 + im * 16 + quad * 4;
#pragma unroll
      for (int r = 0; r < 4; ++r)
        out[(size_t)(row0 + r) * N_DIM + col] = acc[im][in][r] + bv;
    }
  }
}

extern "C" void kernel_launch(void* const* d_in, const int* in_sizes, int n_in,
                              void* d_out, int out_size, void* d_ws, size_t ws_size,
                              hipStream_t stream) {
  const float* X    = (const float*)d_in[0];  // [16384][4096]
  const float* W    = (const float*)d_in[1];  // [4096][4096], out = X @ W^T
  const float* bias = (const float*)d_in[2];  // [4096]
  const float* lA   = (const float*)d_in[3];  // [4096][16]
  const float* lB   = (const float*)d_in[4];  // [16][4096]
  float* out = (float*)d_out;

  bf16_t* T = (bf16_t*)d_ws;                                  // 512 KB
  const size_t offX = 512 * 1024;
  const size_t offW = offX + (size_t)M_DIM * K_DIM * sizeof(bf16_t);
  const size_t need = offW + (size_t)N_DIM * K_DIM * sizeof(bf16_t);

  if (ws_size >= need) {
    bf16_t* Xb = (bf16_t*)((char*)d_ws + offX);
    bf16_t* Wb = (bf16_t*)((char*)d_ws + offW);
    {
      const int n8 = N_DIM * K_DIM / 8;
      cvt_kernel<<<(n8 + 255) / 256, 256, 0, stream>>>(W, Wb, n8);
    }
    // Fused: X fp32 -> (Xb bf16, T) in one pass over X.
    lora_xa_cvt<<<M_DIM / 64, 256, 0, stream>>>(X, lA, T, Xb);
    static bool attr_set = false;
    if (!attr_set) {
      (void)hipFuncSetAttribute(reinterpret_cast<const void*>(main8_bf16),
                                hipFuncAttributeMaxDynamicSharedMemorySize,
                                131072);
      attr_set = true;
    }
    main8_bf16<<<(M_DIM / 256) * (N_DIM / 256), 512, 131072, stream>>>(
        Xb, Wb, bias, lB, T, out);
  } else {
    lora_xa_f32<<<M_DIM / 64, 256, 0, stream>>>(X, lA, T);
    main_f32<<<(M_DIM / 128) * (N_DIM / 128), 256, 0, stream>>>(
        X, W, bias, lB, T, out);
  }
}